// Round 9
// baseline (843.713 us; speedup 1.0000x reference)
//
#include <hip/hip_runtime.h>

typedef _Float16 f16x8 __attribute__((ext_vector_type(8)));
typedef float f32x4 __attribute__((ext_vector_type(4)));

constexpr int D = 256;
constexpr int NUTT = 64;
constexpr int L = 512;
constexpr int G = 768;           // 3*D
constexpr int CHUNK = 128;       // timesteps per producer chunk
constexpr int NCH = L / CHUNK;   // 4 chunks per utterance
constexpr int NBLK = 6;          // 128-col n-blocks over G=768
constexpr int NGEMM = NCH * NUTT * NBLK;   // 1536 producer blocks

// LDS-only barrier: orders ds_* ops across the workgroup WITHOUT draining
// vmcnt — global prefetch loads stay in flight across steps.
__device__ __forceinline__ void lds_barrier() {
  asm volatile("s_waitcnt lgkmcnt(0)\n\ts_barrier" ::: "memory");
}

__device__ __forceinline__ float fast_rcp(float x) {
  return __builtin_amdgcn_rcpf(x);
}
__device__ __forceinline__ float sigm(float x) {
  return fast_rcp(1.0f + __expf(-x));
}
__device__ __forceinline__ float tanh_f(float x) {
  float ax = fabsf(x);
  float e = __expf(-2.0f * ax);
  float r = (1.0f - e) * fast_rcp(1.0f + e);
  return copysignf(r, x);
}

// ---------------------------------------------------------------------------
// Kernel A: pack Wih (f32) -> f16 hi/lo in MFMA fragment order.
// INVERTED vs R8: thread = dst index (coalesced u16 stores), gathered reads.
// Forward map: dst = (((it*8+f)*4+lk)*16+l15)*8+j for src row g=16it+l15,
// col k=32f+8lk+j.  R8's forward version scattered every 2B store.
// Block 0 also zeroes the producer-consumer chunk flags (64B-padded).
// ---------------------------------------------------------------------------
__global__ __launch_bounds__(256) void pack_wih(
    const float* __restrict__ Wih, _Float16* __restrict__ hi,
    _Float16* __restrict__ lo, int* cnt) {
  if (blockIdx.x == 0) cnt[threadIdx.x << 4] = 0;
  const int d = blockIdx.x * 256 + threadIdx.x;    // grid = 768 blocks
  const int j = d & 7;
  const int l15 = (d >> 3) & 15;
  const int lk = (d >> 7) & 3;
  const int f = (d >> 9) & 7;
  const int it = d >> 12;
  const int g = 16 * it + l15;
  const int k = 32 * f + 8 * lk + j;
  float v = Wih[g * 256 + k];
  _Float16 h = (_Float16)v;
  hi[d] = h;
  lo[d] = (_Float16)(v - (float)h);
}

// ---------------------------------------------------------------------------
// Mega-kernel (R8 structure): blocks [0,64) = persistent gru consumers,
// blocks [64,1600) = gemm producers in CHUNK-MAJOR order. Handshake per
// (utt,chunk): release-add after __syncthreads; consumer acquire-spins.
//
// NEW vs R8: the 62-µs attn-pool epilogue is replaced by an ONLINE softmax
// pool computed by wave 4 during the updater phase (its idle window):
// per step, l = h(ts-1)·ua, running max m / denom S / numerator N[256]
// with flash-style rescale — exact f32 math. h-history store to gx is
// DELETED (no consumer). Epilogue = sentence GRU only.
// ---------------------------------------------------------------------------
__global__ __launch_bounds__(512, 2) void hran_mega(
    const int* __restrict__ tokens, const float* __restrict__ embed,
    const _Float16* __restrict__ whi, const _Float16* __restrict__ wlo,
    const float* __restrict__ bih,   // wg_bih
    const float* __restrict__ Whh,   // wg_Whh
    const float* __restrict__ bhh,   // wg_bhh
    const float* __restrict__ uaw,   // ua_w
    const float* __restrict__ sWih, const float* __restrict__ sbih,
    const float* __restrict__ sbhh,
    float* __restrict__ gx,          // [NUTT][L][G]
    int* cnt,                        // 256 flags, 64B-padded
    float* __restrict__ out) {       // [NUTT][D]
  __shared__ __align__(16) _Float16 hbuf[2][D];   // f16 h (mfma A source)
  __shared__ __align__(16) float hbuf32[2][D];    // f32 h (online-attn src)
  __shared__ float pre[3][D];                     // [comp][d] = aR/aZ/aN
  __shared__ __align__(16) float ut[D];           // pooled utterance vec

  const int bx = blockIdx.x;
  const int t = threadIdx.x;
  const int w = t >> 6;               // wave 0..7
  const int lane = t & 63;
  const int l15 = lane & 15;
  const int lk = lane >> 4;

  if (bx >= NUTT) {
    // =================== gemm producer role (R7/R8-verified) =============
    const int gbx = bx - NUTT;
    const int c = gbx / (NUTT * NBLK);         // chunk-major
    const int rem = gbx % (NUTT * NBLK);
    const int u = rem / NBLK;
    const int nb = rem % NBLK;
    const int m0 = u * L + c * CHUNK;          // 128 rows (8 waves x 16)
    const int n0 = nb * 128;
    const int it0 = nb * 8;

    const int tok = tokens[m0 + 16 * w + l15];
    const float* arow = embed + (size_t)tok * D;
    const f16x8* Bh = (const f16x8*)whi;
    const f16x8* Bl = (const f16x8*)wlo;
    const int fragbase = lk * 16 + l15;

    f32x4 acc[8] = {};
#pragma unroll
    for (int f = 0; f < 8; ++f) {
      const float* ap = arow + 32 * f + 8 * lk;
      float4 v0 = *(const float4*)(ap);
      float4 v1 = *(const float4*)(ap + 4);
      float av[8] = {v0.x, v0.y, v0.z, v0.w, v1.x, v1.y, v1.z, v1.w};
      f16x8 ahi, alo;
#pragma unroll
      for (int j = 0; j < 8; ++j) {
        _Float16 h = (_Float16)av[j];
        ahi[j] = h;
        alo[j] = (_Float16)(av[j] - (float)h);
      }
#pragma unroll
      for (int i = 0; i < 8; ++i) {
        const int frag = ((it0 + i) * 8 + f) * 64 + fragbase;
        f16x8 bhi = Bh[frag];
        f16x8 blo = Bl[frag];
        acc[i] = __builtin_amdgcn_mfma_f32_16x16x32_f16(ahi, bhi, acc[i], 0, 0, 0);
        acc[i] = __builtin_amdgcn_mfma_f32_16x16x32_f16(alo, bhi, acc[i], 0, 0, 0);
        acc[i] = __builtin_amdgcn_mfma_f32_16x16x32_f16(ahi, blo, acc[i], 0, 0, 0);
      }
    }
#pragma unroll
    for (int i = 0; i < 8; ++i) {
      const int n = n0 + 16 * i + l15;
      const float bb = bih[n];
#pragma unroll
      for (int reg = 0; reg < 4; ++reg) {
        const int m = m0 + 16 * w + 4 * lk + reg;
        gx[(size_t)m * G + n] = acc[i][reg] + bb;
      }
    }
    __syncthreads();                 // drains vmcnt: all stores issued
    if (t == 0)
      __hip_atomic_fetch_add(&cnt[((u << 2) + c) << 4], 1,
                             __ATOMIC_RELEASE, __HIP_MEMORY_SCOPE_AGENT);
    return;
  }

  // ====================== gru consumer role ==============================
  const int b = bx;

  // ---- Bf[i][f][j] = Whh[96w + 16i + l15][32f + 8lk + j], f16 ----
  f16x8 Bf[6][8];
#pragma unroll
  for (int i = 0; i < 6; ++i) {
    const float* row = Whh + (size_t)(96 * w + 16 * i + l15) * D + 8 * lk;
#pragma unroll
    for (int f = 0; f < 8; ++f) {
      float4 v0 = *(const float4*)(row + 32 * f);
      float4 v1 = *(const float4*)(row + 32 * f + 4);
      Bf[i][f] = f16x8{(_Float16)v0.x, (_Float16)v0.y,
                       (_Float16)v0.z, (_Float16)v0.w,
                       (_Float16)v1.x, (_Float16)v1.y,
                       (_Float16)v1.z, (_Float16)v1.w};
    }
  }

  float bR = 0.0f, bZ = 0.0f, bN = 0.0f;
  float gr = 0.0f, gz = 0.0f, gn = 0.0f;
  float hprev = 0.0f;
  float* gxb = gx + (size_t)b * L * G;
  if (t < 256) {
    bR = bhh[t]; bZ = bhh[D + t]; bN = bhh[2 * D + t];
    hbuf[0][t] = (_Float16)0.0f;
  }

  // online-softmax state (wave 4): lane owns dims 4*lane .. 4*lane+3
  float am = -1e30f, aS = 0.0f;
  float4 aN = {0.0f, 0.0f, 0.0f, 0.0f};
  float4 uav = {0.0f, 0.0f, 0.0f, 0.0f};
  if (w == 4) uav = *(const float4*)(uaw + 4 * lane);
  __syncthreads();

  for (int c = 0; c < NCH; ++c) {
    // wait for this utterance's chunk c (6 producer blocks)
    if (t == 0) {
      while (__hip_atomic_load(&cnt[((b << 2) + c) << 4],
                               __ATOMIC_ACQUIRE,
                               __HIP_MEMORY_SCOPE_AGENT) < NBLK)
        __builtin_amdgcn_s_sleep(8);
    }
    __syncthreads();
    __threadfence();
    if (t < 256) {                   // chunk-entry g* load
      const float* gc = gxb + (size_t)(CHUNK * c) * G;
      gr = gc[t]; gz = gc[D + t]; gn = gc[2 * D + t];
    }

    for (int tsl = 0; tsl < CHUNK; ++tsl) {
      const int ts = CHUNK * c + tsl;
      const int cur = ts & 1;
      const _Float16* hb = hbuf[cur];
      f16x8 A[8];
#pragma unroll
      for (int f = 0; f < 8; ++f)
        A[f] = *(const f16x8*)(hb + 32 * f + 8 * lk);

#pragma unroll
      for (int i = 0; i < 6; ++i) {
        f32x4 acc = {0.0f, 0.0f, 0.0f, 0.0f};
#pragma unroll
        for (int f = 0; f < 8; ++f)
          acc = __builtin_amdgcn_mfma_f32_16x16x32_f16(A[f], Bf[i][f], acc,
                                                       0, 0, 0);
        if (lk == 0) {                // all D rows equal; lanes 0-15 publish
          const int n = 96 * w + 16 * i + l15;
          pre[n >> 8][n & 255] = acc[0];
        }
      }
      lds_barrier();

      if (t < 256) {
        // ---------------- gate update (waves 0-3) ----------------
        float aR = pre[0][t], aZ = pre[1][t], aNp = pre[2][t];
        float r = sigm(gr + aR + bR);
        float z = sigm(gz + aZ + bZ);
        float nn = tanh_f(gn + r * (aNp + bN));
        float hn = fmaf(z, hprev - nn, nn);    // (1-z)*n + z*h
        hprev = hn;
        hbuf[cur ^ 1][t] = (_Float16)hn;
        hbuf32[cur ^ 1][t] = hn;
        const int tn = ts + 1;
        if (tn & (CHUNK - 1)) {                // within chunk: prefetch
          const float* gxn = gxb + (size_t)tn * G;
          gr = gxn[t]; gz = gxn[D + t]; gn = gxn[2 * D + t];
        }
      } else if (w == 4 && ts > 0) {
        // -------- online softmax pool of h(ts-1) (wave 4) --------
        // h(ts-1) was written at step ts-1 into hbuf32[(ts-1)&1 ^ 1] ==
        // hbuf32[cur]; the updater writes hbuf32[cur^1] — no overlap.
        float4 hv = *(const float4*)(&hbuf32[cur][4 * lane]);
        float lp = hv.x * uav.x + hv.y * uav.y + hv.z * uav.z + hv.w * uav.w;
#pragma unroll
        for (int off = 32; off; off >>= 1) lp += __shfl_xor(lp, off);
        float mn = fmaxf(am, lp);
        float cs = __expf(am - mn);
        float wg = __expf(lp - mn);
        aS = aS * cs + wg;
        aN.x = aN.x * cs + wg * hv.x;
        aN.y = aN.y * cs + wg * hv.y;
        aN.z = aN.z * cs + wg * hv.z;
        aN.w = aN.w * cs + wg * hv.w;
        am = mn;
      }
      lds_barrier();
    }
  }

  // ===== epilogue: final attn update + sentence GRU (block-local) =====
  if (w == 4) {
    // h(511) sits in hbuf32[(511&1)^1] = hbuf32[0]
    float4 hv = *(const float4*)(&hbuf32[0][4 * lane]);
    float lp = hv.x * uav.x + hv.y * uav.y + hv.z * uav.z + hv.w * uav.w;
#pragma unroll
    for (int off = 32; off; off >>= 1) lp += __shfl_xor(lp, off);
    float mn = fmaxf(am, lp);
    float cs = __expf(am - mn);
    float wg = __expf(lp - mn);
    aS = aS * cs + wg;
    aN.x = aN.x * cs + wg * hv.x;
    aN.y = aN.y * cs + wg * hv.y;
    aN.z = aN.z * cs + wg * hv.z;
    aN.w = aN.w * cs + wg * hv.w;
    float inv = 1.0f / aS;
    float4 uo = {aN.x * inv, aN.y * inv, aN.z * inv, aN.w * inv};
    *(float4*)(&ut[4 * lane]) = uo;
  }
  __syncthreads();

  // sentence GRU (T=1, h0=0) -> out = (1-z)*n
  if (t < 256) {
    const int d = t;
    const float* wr = sWih + (size_t)d * D;
    const float* wz = sWih + (size_t)(D + d) * D;
    const float* wn = sWih + (size_t)(2 * D + d) * D;
    float ar = 0.0f, az = 0.0f, an = 0.0f;
    for (int k = 0; k < D; k += 4) {
      float4 vr = *(const float4*)(wr + k);
      float4 vz = *(const float4*)(wz + k);
      float4 vn = *(const float4*)(wn + k);
      float u0 = ut[k], u1 = ut[k + 1], u2 = ut[k + 2], u3 = ut[k + 3];
      ar += vr.x * u0 + vr.y * u1 + vr.z * u2 + vr.w * u3;
      az += vz.x * u0 + vz.y * u1 + vz.z * u2 + vz.w * u3;
      an += vn.x * u0 + vn.y * u1 + vn.z * u2 + vn.w * u3;
    }
    float r = sigm(ar + sbih[d] + sbhh[d]);
    float z = sigm(az + sbih[D + d] + sbhh[D + d]);
    float n = tanh_f(an + sbih[2 * D + d] + r * sbhh[2 * D + d]);
    out[(size_t)b * D + d] = (1.0f - z) * n;
  }
}

// ---------------------------------------------------------------------------
extern "C" void kernel_launch(void* const* d_in, const int* in_sizes, int n_in,
                              void* d_out, int out_size, void* d_ws, size_t ws_size,
                              hipStream_t stream) {
  const int* tokens    = (const int*)d_in[0];
  const float* embed   = (const float*)d_in[1];
  const float* wg_Wih  = (const float*)d_in[2];
  const float* wg_Whh  = (const float*)d_in[3];
  const float* wg_bih  = (const float*)d_in[4];
  const float* wg_bhh  = (const float*)d_in[5];
  const float* ua_w    = (const float*)d_in[6];
  // d_in[7] ua_b: softmax shift-invariant -> unused
  const float* sg_Wih  = (const float*)d_in[8];
  // d_in[9] sg_Whh: h0 == 0 -> unused
  const float* sg_bih  = (const float*)d_in[10];
  const float* sg_bhh  = (const float*)d_in[11];
  // d_in[12..13] da_w/da_b: softmax over T=1 -> unused
  float* out = (float*)d_out;

  char* ws = (char*)d_ws;
  const size_t GXB = (size_t)NUTT * L * G * 4;                 // 96 MB
  float* gx = (float*)ws;
  _Float16* whi = (_Float16*)(ws + GXB);                       // 384 KB
  _Float16* wlo = whi + (size_t)G * D;                         // 384 KB
  int* cnt = (int*)(ws + GXB + (size_t)2 * G * D * 2);         // 16 KB flags

  pack_wih<<<G, 256, 0, stream>>>(wg_Wih, whi, wlo, cnt);
  hran_mega<<<NUTT + NGEMM, 512, 0, stream>>>(
      tokens, embed, whi, wlo, wg_bih, wg_Whh, wg_bhh, ua_w,
      sg_Wih, sg_bih, sg_bhh, gx, cnt, out);
}

// Round 10
// 836.841 us; speedup vs baseline: 1.0082x; 1.0082x over previous
//
#include <hip/hip_runtime.h>

typedef _Float16 f16x8 __attribute__((ext_vector_type(8)));
typedef float f32x4 __attribute__((ext_vector_type(4)));

constexpr int D = 256;
constexpr int NUTT = 64;
constexpr int L = 512;
constexpr int G = 768;           // 3*D
constexpr int CHUNK = 128;       // timesteps per producer chunk
constexpr int NCH = L / CHUNK;   // 4 chunks per utterance
constexpr int NBLK = 6;          // 128-col n-blocks over G=768
constexpr int NGEMM = NCH * NUTT * NBLK;   // 1536 producer blocks

// LDS-only barrier: orders ds_* ops across the workgroup WITHOUT draining
// vmcnt — global prefetch loads / wo16 stores stay in flight across steps.
__device__ __forceinline__ void lds_barrier() {
  asm volatile("s_waitcnt lgkmcnt(0)\n\ts_barrier" ::: "memory");
}

__device__ __forceinline__ float fast_rcp(float x) {
  return __builtin_amdgcn_rcpf(x);
}
__device__ __forceinline__ float sigm(float x) {
  return fast_rcp(1.0f + __expf(-x));
}
__device__ __forceinline__ float tanh_f(float x) {
  float ax = fabsf(x);
  float e = __expf(-2.0f * ax);
  float r = (1.0f - e) * fast_rcp(1.0f + e);
  return copysignf(r, x);
}

// ---------------------------------------------------------------------------
// Kernel A: pack Wih (f32) -> f16 hi/lo in MFMA fragment order (R9-verified,
// inverted map: thread = dst index, coalesced stores).
// Block 0 also zeroes the producer-consumer chunk flags (64B-padded).
// ---------------------------------------------------------------------------
__global__ __launch_bounds__(256) void pack_wih(
    const float* __restrict__ Wih, _Float16* __restrict__ hi,
    _Float16* __restrict__ lo, int* cnt) {
  if (blockIdx.x == 0) cnt[threadIdx.x << 4] = 0;
  const int d = blockIdx.x * 256 + threadIdx.x;    // grid = 768 blocks
  const int j = d & 7;
  const int l15 = (d >> 3) & 15;
  const int lk = (d >> 7) & 3;
  const int f = (d >> 9) & 7;
  const int it = d >> 12;
  const int g = 16 * it + l15;
  const int k = 32 * f + 8 * lk + j;
  float v = Wih[g * 256 + k];
  _Float16 h = (_Float16)v;
  hi[d] = h;
  lo[d] = (_Float16)(v - (float)h);
}

// ---------------------------------------------------------------------------
// Mega-kernel (R8 producer-consumer structure; R9's online-softmax REVERTED
// — its serial rescale chain exceeded the updater shadow, +280 cyc/step).
// This round keeps only the dependency-free part online:
//   phase 2, waves 4-7: partial logit dot of h(ts-1) (64 dims/wave, 1 LDS
//   float + 1 mul + 6 shfl, no cross-step chain) -> plg[ts-1][q].
//   updater additionally stores h as f16 to wo16 (coalesced 2B/thread).
// Epilogue: sum partials -> softmax over 512 scalars -> f16 weighted sum
// (16 MB vs R8's 32 MB f32 + no logits pass) -> sentence GRU.
// ---------------------------------------------------------------------------
__global__ __launch_bounds__(512, 2) void hran_mega(
    const int* __restrict__ tokens, const float* __restrict__ embed,
    const _Float16* __restrict__ whi, const _Float16* __restrict__ wlo,
    const float* __restrict__ bih,   // wg_bih
    const float* __restrict__ Whh,   // wg_Whh
    const float* __restrict__ bhh,   // wg_bhh
    const float* __restrict__ uaw,   // ua_w
    const float* __restrict__ sWih, const float* __restrict__ sbih,
    const float* __restrict__ sbhh,
    float* __restrict__ gx,          // [NUTT][L][G]
    _Float16* __restrict__ wo16,     // [NUTT][L][D] f16 h history
    int* cnt,                        // 256 flags, 64B-padded
    float* __restrict__ out) {       // [NUTT][D]
  __shared__ __align__(16) _Float16 hbuf[2][D];   // f16 h (mfma A source)
  __shared__ __align__(16) float hbuf32[2][D];    // f32 h (logit source)
  __shared__ float pre[3][D];                     // [comp][d] = aR/aZ/aN
  __shared__ float plg[L][4];                     // per-step logit partials
  __shared__ float lg[L];
  __shared__ float red[16];
  __shared__ float part[D];
  __shared__ __align__(16) float ut[D];

  const int bx = blockIdx.x;
  const int t = threadIdx.x;
  const int w = t >> 6;               // wave 0..7
  const int lane = t & 63;
  const int l15 = lane & 15;
  const int lk = lane >> 4;

  if (bx >= NUTT) {
    // =================== gemm producer role (R7/R8-verified) =============
    const int gbx = bx - NUTT;
    const int c = gbx / (NUTT * NBLK);         // chunk-major
    const int rem = gbx % (NUTT * NBLK);
    const int u = rem / NBLK;
    const int nb = rem % NBLK;
    const int m0 = u * L + c * CHUNK;          // 128 rows (8 waves x 16)
    const int n0 = nb * 128;
    const int it0 = nb * 8;

    const int tok = tokens[m0 + 16 * w + l15];
    const float* arow = embed + (size_t)tok * D;
    const f16x8* Bh = (const f16x8*)whi;
    const f16x8* Bl = (const f16x8*)wlo;
    const int fragbase = lk * 16 + l15;

    f32x4 acc[8] = {};
#pragma unroll
    for (int f = 0; f < 8; ++f) {
      const float* ap = arow + 32 * f + 8 * lk;
      float4 v0 = *(const float4*)(ap);
      float4 v1 = *(const float4*)(ap + 4);
      float av[8] = {v0.x, v0.y, v0.z, v0.w, v1.x, v1.y, v1.z, v1.w};
      f16x8 ahi, alo;
#pragma unroll
      for (int j = 0; j < 8; ++j) {
        _Float16 h = (_Float16)av[j];
        ahi[j] = h;
        alo[j] = (_Float16)(av[j] - (float)h);
      }
#pragma unroll
      for (int i = 0; i < 8; ++i) {
        const int frag = ((it0 + i) * 8 + f) * 64 + fragbase;
        f16x8 bhi = Bh[frag];
        f16x8 blo = Bl[frag];
        acc[i] = __builtin_amdgcn_mfma_f32_16x16x32_f16(ahi, bhi, acc[i], 0, 0, 0);
        acc[i] = __builtin_amdgcn_mfma_f32_16x16x32_f16(alo, bhi, acc[i], 0, 0, 0);
        acc[i] = __builtin_amdgcn_mfma_f32_16x16x32_f16(ahi, blo, acc[i], 0, 0, 0);
      }
    }
#pragma unroll
    for (int i = 0; i < 8; ++i) {
      const int n = n0 + 16 * i + l15;
      const float bb = bih[n];
#pragma unroll
      for (int reg = 0; reg < 4; ++reg) {
        const int m = m0 + 16 * w + 4 * lk + reg;
        gx[(size_t)m * G + n] = acc[i][reg] + bb;
      }
    }
    __syncthreads();                 // drains vmcnt: all stores issued
    if (t == 0)
      __hip_atomic_fetch_add(&cnt[((u << 2) + c) << 4], 1,
                             __ATOMIC_RELEASE, __HIP_MEMORY_SCOPE_AGENT);
    return;
  }

  // ====================== gru consumer role ==============================
  const int b = bx;

  // ---- Bf[i][f][j] = Whh[96w + 16i + l15][32f + 8lk + j], f16 ----
  f16x8 Bf[6][8];
#pragma unroll
  for (int i = 0; i < 6; ++i) {
    const float* row = Whh + (size_t)(96 * w + 16 * i + l15) * D + 8 * lk;
#pragma unroll
    for (int f = 0; f < 8; ++f) {
      float4 v0 = *(const float4*)(row + 32 * f);
      float4 v1 = *(const float4*)(row + 32 * f + 4);
      Bf[i][f] = f16x8{(_Float16)v0.x, (_Float16)v0.y,
                       (_Float16)v0.z, (_Float16)v0.w,
                       (_Float16)v1.x, (_Float16)v1.y,
                       (_Float16)v1.z, (_Float16)v1.w};
    }
  }

  float bR = 0.0f, bZ = 0.0f, bN = 0.0f;
  float gr = 0.0f, gz = 0.0f, gn = 0.0f;
  float hprev = 0.0f;
  float* gxb = gx + (size_t)b * L * G;
  _Float16* wob = wo16 + (size_t)b * L * D;
  if (t < 256) {
    bR = bhh[t]; bZ = bhh[D + t]; bN = bhh[2 * D + t];
    hbuf[0][t] = (_Float16)0.0f;
  }
  // logit-partial setup (waves 4-7): wave q owns dims [64q, 64q+64)
  const int q = w - 4;
  float uaq = 0.0f;
  if (w >= 4) uaq = uaw[64 * q + lane];
  __syncthreads();

  for (int c = 0; c < NCH; ++c) {
    // wait for this utterance's chunk c (6 producer blocks)
    if (t == 0) {
      while (__hip_atomic_load(&cnt[((b << 2) + c) << 4],
                               __ATOMIC_ACQUIRE,
                               __HIP_MEMORY_SCOPE_AGENT) < NBLK)
        __builtin_amdgcn_s_sleep(8);
    }
    __syncthreads();
    __threadfence();
    if (t < 256) {                   // chunk-entry g* load
      const float* gc = gxb + (size_t)(CHUNK * c) * G;
      gr = gc[t]; gz = gc[D + t]; gn = gc[2 * D + t];
    }

    for (int tsl = 0; tsl < CHUNK; ++tsl) {
      const int ts = CHUNK * c + tsl;
      const int cur = ts & 1;
      const _Float16* hb = hbuf[cur];
      f16x8 A[8];
#pragma unroll
      for (int f = 0; f < 8; ++f)
        A[f] = *(const f16x8*)(hb + 32 * f + 8 * lk);

#pragma unroll
      for (int i = 0; i < 6; ++i) {
        f32x4 acc = {0.0f, 0.0f, 0.0f, 0.0f};
#pragma unroll
        for (int f = 0; f < 8; ++f)
          acc = __builtin_amdgcn_mfma_f32_16x16x32_f16(A[f], Bf[i][f], acc,
                                                       0, 0, 0);
        if (lk == 0) {                // all D rows equal; lanes 0-15 publish
          const int n = 96 * w + 16 * i + l15;
          pre[n >> 8][n & 255] = acc[0];
        }
      }
      lds_barrier();

      if (t < 256) {
        // ---------------- gate update (waves 0-3) ----------------
        float aR = pre[0][t], aZ = pre[1][t], aNp = pre[2][t];
        float r = sigm(gr + aR + bR);
        float z = sigm(gz + aZ + bZ);
        float nn = tanh_f(gn + r * (aNp + bN));
        float hn = fmaf(z, hprev - nn, nn);    // (1-z)*n + z*h
        hprev = hn;
        _Float16 hf = (_Float16)hn;
        hbuf[cur ^ 1][t] = hf;
        hbuf32[cur ^ 1][t] = hn;
        wob[(size_t)ts * D + t] = hf;          // f16 history (coalesced)
        const int tn = ts + 1;
        if (tn & (CHUNK - 1)) {                // within chunk: prefetch
          const float* gxn = gxb + (size_t)tn * G;
          gr = gxn[t]; gz = gxn[D + t]; gn = gxn[2 * D + t];
        }
      } else if (ts > 0) {
        // ------ logit partial of h(ts-1) (waves 4-7, no chain) ------
        // h(ts-1) lives in hbuf32[cur]; updater writes hbuf32[cur^1].
        float p = hbuf32[cur][64 * q + lane] * uaq;
#pragma unroll
        for (int off = 32; off; off >>= 1) p += __shfl_xor(p, off);
        if (lane == 0) plg[ts - 1][q] = p;
      }
      lds_barrier();
    }
  }

  // ===== epilogue: logit 511, softmax, f16 weighted sum, sentence GRU ====
  if (w >= 4) {
    // h(511) sits in hbuf32[(511&1)^1] = hbuf32[0]
    float p = hbuf32[0][64 * q + lane] * uaq;
#pragma unroll
    for (int off = 32; off; off >>= 1) p += __shfl_xor(p, off);
    if (lane == 0) plg[511][q] = p;
  }
  __syncthreads();
  lg[t] = plg[t][0] + plg[t][1] + plg[t][2] + plg[t][3];
  __syncthreads();

  // softmax over 512 logits (thread t owns lg[t]) — R7-verified code
  {
    float v = lg[t];
    float m = v;
#pragma unroll
    for (int off = 32; off; off >>= 1) m = fmaxf(m, __shfl_xor(m, off));
    if (lane == 0) red[w] = m;
    __syncthreads();
    m = red[0];
#pragma unroll
    for (int i = 1; i < 8; ++i) m = fmaxf(m, red[i]);
    float e = __expf(v - m);
    float s = e;
#pragma unroll
    for (int off = 32; off; off >>= 1) s += __shfl_xor(s, off);
    if (lane == 0) red[8 + w] = s;
    __syncthreads();
    s = red[8];
#pragma unroll
    for (int i = 9; i < 16; ++i) s += red[i];
    lg[t] = e * (1.0f / s);
  }
  __syncthreads();

  // weighted sum over f16 history: half 0 sums ts in [0,256), half 1 rest
  {
    asm volatile("s_waitcnt vmcnt(0)" ::: "memory");   // wo16 stores done
    const int d = t & 255, half = t >> 8;
    float acc = 0.0f;
    const _Float16* bbp = wob + (size_t)half * 256 * D;
    const float* lgh = lg + half * 256;
#pragma unroll 4
    for (int k = 0; k < 256; ++k)
      acc = fmaf(lgh[k], (float)bbp[(size_t)k * D + d], acc);
    if (half == 1) part[d] = acc;
    __syncthreads();
    if (half == 0) ut[d] = acc + part[d];
    __syncthreads();
  }

  // sentence GRU (T=1, h0=0) -> out = (1-z)*n
  if (t < 256) {
    const int d = t;
    const float* wr = sWih + (size_t)d * D;
    const float* wz = sWih + (size_t)(D + d) * D;
    const float* wn = sWih + (size_t)(2 * D + d) * D;
    float ar = 0.0f, az = 0.0f, an = 0.0f;
    for (int k = 0; k < D; k += 4) {
      float4 vr = *(const float4*)(wr + k);
      float4 vz = *(const float4*)(wz + k);
      float4 vn = *(const float4*)(wn + k);
      float u0 = ut[k], u1 = ut[k + 1], u2 = ut[k + 2], u3 = ut[k + 3];
      ar += vr.x * u0 + vr.y * u1 + vr.z * u2 + vr.w * u3;
      az += vz.x * u0 + vz.y * u1 + vz.z * u2 + vz.w * u3;
      an += vn.x * u0 + vn.y * u1 + vn.z * u2 + vn.w * u3;
    }
    float r = sigm(ar + sbih[d] + sbhh[d]);
    float z = sigm(az + sbih[D + d] + sbhh[D + d]);
    float n = tanh_f(an + sbih[2 * D + d] + r * sbhh[2 * D + d]);
    out[(size_t)b * D + d] = (1.0f - z) * n;
  }
}

// ---------------------------------------------------------------------------
extern "C" void kernel_launch(void* const* d_in, const int* in_sizes, int n_in,
                              void* d_out, int out_size, void* d_ws, size_t ws_size,
                              hipStream_t stream) {
  const int* tokens    = (const int*)d_in[0];
  const float* embed   = (const float*)d_in[1];
  const float* wg_Wih  = (const float*)d_in[2];
  const float* wg_Whh  = (const float*)d_in[3];
  const float* wg_bih  = (const float*)d_in[4];
  const float* wg_bhh  = (const float*)d_in[5];
  const float* ua_w    = (const float*)d_in[6];
  // d_in[7] ua_b: softmax shift-invariant -> unused
  const float* sg_Wih  = (const float*)d_in[8];
  // d_in[9] sg_Whh: h0 == 0 -> unused
  const float* sg_bih  = (const float*)d_in[10];
  const float* sg_bhh  = (const float*)d_in[11];
  // d_in[12..13] da_w/da_b: softmax over T=1 -> unused
  float* out = (float*)d_out;

  char* ws = (char*)d_ws;
  const size_t GXB = (size_t)NUTT * L * G * 4;                 // 96 MB
  float* gx = (float*)ws;
  _Float16* whi = (_Float16*)(ws + GXB);                       // 384 KB
  _Float16* wlo = whi + (size_t)G * D;                         // 384 KB
  int* cnt = (int*)(ws + GXB + (size_t)2 * G * D * 2);         // 16 KB flags
  _Float16* wo16 = (_Float16*)(ws + GXB + (size_t)2 * G * D * 2 + 16384);

  pack_wih<<<G, 256, 0, stream>>>(wg_Wih, whi, wlo, cnt);
  hran_mega<<<NUTT + NGEMM, 512, 0, stream>>>(
      tokens, embed, whi, wlo, wg_bih, wg_Whh, wg_bhh, ua_w,
      sg_Wih, sg_bih, sg_bhh, gx, wo16, cnt, out);
}

// Round 11
// 776.249 us; speedup vs baseline: 1.0869x; 1.0781x over previous
//
#include <hip/hip_runtime.h>

typedef _Float16 f16x8 __attribute__((ext_vector_type(8)));
typedef float f32x4 __attribute__((ext_vector_type(4)));

constexpr int D = 256;
constexpr int NUTT = 64;
constexpr int L = 512;
constexpr int G = 768;           // 3*D
constexpr int CHUNK = 128;       // timesteps per producer chunk
constexpr int NCH = L / CHUNK;   // 4 chunks per utterance
constexpr int NBLK = 6;          // 128-col n-blocks over G=768
constexpr int NGEMM = NCH * NUTT * NBLK;   // 1536 producer blocks

// LDS-only barrier: orders ds_* ops across the workgroup WITHOUT draining
// vmcnt — global prefetch loads / wo16 stores stay in flight across steps.
__device__ __forceinline__ void lds_barrier() {
  asm volatile("s_waitcnt lgkmcnt(0)\n\ts_barrier" ::: "memory");
}

__device__ __forceinline__ float fast_rcp(float x) {
  return __builtin_amdgcn_rcpf(x);
}
__device__ __forceinline__ float sigm(float x) {
  return fast_rcp(1.0f + __expf(-x));
}
__device__ __forceinline__ float tanh_f(float x) {
  float ax = fabsf(x);
  float e = __expf(-2.0f * ax);
  float r = (1.0f - e) * fast_rcp(1.0f + e);
  return copysignf(r, x);
}

// ---------------------------------------------------------------------------
// Kernel A: pack Wih (f32) -> f16 hi/lo in MFMA fragment order (R9-verified,
// inverted map: thread = dst index, coalesced stores).
// Block 0 also zeroes the producer-consumer chunk flags (64B-padded).
// ---------------------------------------------------------------------------
__global__ __launch_bounds__(256) void pack_wih(
    const float* __restrict__ Wih, _Float16* __restrict__ hi,
    _Float16* __restrict__ lo, int* cnt) {
  if (blockIdx.x == 0) cnt[threadIdx.x << 4] = 0;
  const int d = blockIdx.x * 256 + threadIdx.x;    // grid = 768 blocks
  const int j = d & 7;
  const int l15 = (d >> 3) & 15;
  const int lk = (d >> 7) & 3;
  const int f = (d >> 9) & 7;
  const int it = d >> 12;
  const int g = 16 * it + l15;
  const int k = 32 * f + 8 * lk + j;
  float v = Wih[g * 256 + k];
  _Float16 h = (_Float16)v;
  hi[d] = h;
  lo[d] = (_Float16)(v - (float)h);
}

// ---------------------------------------------------------------------------
// Mega-kernel — R8 scan structure restored EXACTLY (verified ~640 µs pace;
// R9/R10's in-shadow pooling attempts both lost: serial shfl_xor chains
// route through the LDS crossbar, ~350-400 cyc > the updater's ~200-cyc
// gate chain, extending phase 2 every step. Idle waves are cheaper.)
// Blocks [0,64) = persistent gru consumers; [64,1600) = gemm producers in
// chunk-major order; release/acquire handshake per (utt,chunk).
// Changes vs R8: h history stored as f16 into compact wo16 (coalesced 512B
// stores; halves epilogue read traffic; numerics validated in R10), and the
// fused epilogue (logits/softmax/weighted-sum/sentence-GRU) reads f16.
// ---------------------------------------------------------------------------
__global__ __launch_bounds__(512, 2) void hran_mega(
    const int* __restrict__ tokens, const float* __restrict__ embed,
    const _Float16* __restrict__ whi, const _Float16* __restrict__ wlo,
    const float* __restrict__ bih,   // wg_bih
    const float* __restrict__ Whh,   // wg_Whh
    const float* __restrict__ bhh,   // wg_bhh
    const float* __restrict__ uaw,   // ua_w
    const float* __restrict__ sWih, const float* __restrict__ sbih,
    const float* __restrict__ sbhh,
    float* __restrict__ gx,          // [NUTT][L][G]
    _Float16* __restrict__ wo16,     // [NUTT][L][D] f16 h history
    int* cnt,                        // 256 flags, 64B-padded
    float* __restrict__ out) {       // [NUTT][D]
  __shared__ __align__(16) _Float16 hbuf[2][D];   // f16 h, double-buffered
  __shared__ float pre[3][D];                     // [comp][d] = aR/aZ/aN
  __shared__ float lg[L];
  __shared__ float red[16];
  __shared__ float part[D];
  __shared__ __align__(16) float ut[D];

  const int bx = blockIdx.x;
  const int t = threadIdx.x;
  const int w = t >> 6;               // wave 0..7
  const int lane = t & 63;
  const int l15 = lane & 15;
  const int lk = lane >> 4;

  if (bx >= NUTT) {
    // =================== gemm producer role (R7/R8-verified) =============
    const int gbx = bx - NUTT;
    const int c = gbx / (NUTT * NBLK);         // chunk-major
    const int rem = gbx % (NUTT * NBLK);
    const int u = rem / NBLK;
    const int nb = rem % NBLK;
    const int m0 = u * L + c * CHUNK;          // 128 rows (8 waves x 16)
    const int n0 = nb * 128;
    const int it0 = nb * 8;

    const int tok = tokens[m0 + 16 * w + l15];
    const float* arow = embed + (size_t)tok * D;
    const f16x8* Bh = (const f16x8*)whi;
    const f16x8* Bl = (const f16x8*)wlo;
    const int fragbase = lk * 16 + l15;

    f32x4 acc[8] = {};
#pragma unroll
    for (int f = 0; f < 8; ++f) {
      const float* ap = arow + 32 * f + 8 * lk;
      float4 v0 = *(const float4*)(ap);
      float4 v1 = *(const float4*)(ap + 4);
      float av[8] = {v0.x, v0.y, v0.z, v0.w, v1.x, v1.y, v1.z, v1.w};
      f16x8 ahi, alo;
#pragma unroll
      for (int j = 0; j < 8; ++j) {
        _Float16 h = (_Float16)av[j];
        ahi[j] = h;
        alo[j] = (_Float16)(av[j] - (float)h);
      }
#pragma unroll
      for (int i = 0; i < 8; ++i) {
        const int frag = ((it0 + i) * 8 + f) * 64 + fragbase;
        f16x8 bhi = Bh[frag];
        f16x8 blo = Bl[frag];
        acc[i] = __builtin_amdgcn_mfma_f32_16x16x32_f16(ahi, bhi, acc[i], 0, 0, 0);
        acc[i] = __builtin_amdgcn_mfma_f32_16x16x32_f16(alo, bhi, acc[i], 0, 0, 0);
        acc[i] = __builtin_amdgcn_mfma_f32_16x16x32_f16(ahi, blo, acc[i], 0, 0, 0);
      }
    }
#pragma unroll
    for (int i = 0; i < 8; ++i) {
      const int n = n0 + 16 * i + l15;
      const float bb = bih[n];
#pragma unroll
      for (int reg = 0; reg < 4; ++reg) {
        const int m = m0 + 16 * w + 4 * lk + reg;
        gx[(size_t)m * G + n] = acc[i][reg] + bb;
      }
    }
    __syncthreads();                 // drains vmcnt: all stores issued
    if (t == 0)
      __hip_atomic_fetch_add(&cnt[((u << 2) + c) << 4], 1,
                             __ATOMIC_RELEASE, __HIP_MEMORY_SCOPE_AGENT);
    return;
  }

  // ====================== gru consumer role ==============================
  const int b = bx;

  // ---- Bf[i][f][j] = Whh[96w + 16i + l15][32f + 8lk + j], f16 ----
  f16x8 Bf[6][8];
#pragma unroll
  for (int i = 0; i < 6; ++i) {
    const float* row = Whh + (size_t)(96 * w + 16 * i + l15) * D + 8 * lk;
#pragma unroll
    for (int f = 0; f < 8; ++f) {
      float4 v0 = *(const float4*)(row + 32 * f);
      float4 v1 = *(const float4*)(row + 32 * f + 4);
      Bf[i][f] = f16x8{(_Float16)v0.x, (_Float16)v0.y,
                       (_Float16)v0.z, (_Float16)v0.w,
                       (_Float16)v1.x, (_Float16)v1.y,
                       (_Float16)v1.z, (_Float16)v1.w};
    }
  }

  float bR = 0.0f, bZ = 0.0f, bN = 0.0f;
  float gr = 0.0f, gz = 0.0f, gn = 0.0f;
  float hprev = 0.0f;
  float* gxb = gx + (size_t)b * L * G;
  _Float16* wob = wo16 + (size_t)b * L * D;
  if (t < 256) {
    bR = bhh[t]; bZ = bhh[D + t]; bN = bhh[2 * D + t];
    hbuf[0][t] = (_Float16)0.0f;
  }
  __syncthreads();

  for (int c = 0; c < NCH; ++c) {
    // wait for this utterance's chunk c (6 producer blocks)
    if (t == 0) {
      while (__hip_atomic_load(&cnt[((b << 2) + c) << 4],
                               __ATOMIC_ACQUIRE,
                               __HIP_MEMORY_SCOPE_AGENT) < NBLK)
        __builtin_amdgcn_s_sleep(8);
    }
    __syncthreads();
    __threadfence();
    if (t < 256) {                   // chunk-entry g* load
      const float* gc = gxb + (size_t)(CHUNK * c) * G;
      gr = gc[t]; gz = gc[D + t]; gn = gc[2 * D + t];
    }

    for (int tsl = 0; tsl < CHUNK; ++tsl) {
      const int ts = CHUNK * c + tsl;
      const int cur = ts & 1;
      const _Float16* hb = hbuf[cur];
      f16x8 A[8];
#pragma unroll
      for (int f = 0; f < 8; ++f)
        A[f] = *(const f16x8*)(hb + 32 * f + 8 * lk);

#pragma unroll
      for (int i = 0; i < 6; ++i) {
        f32x4 acc = {0.0f, 0.0f, 0.0f, 0.0f};
#pragma unroll
        for (int f = 0; f < 8; ++f)
          acc = __builtin_amdgcn_mfma_f32_16x16x32_f16(A[f], Bf[i][f], acc,
                                                       0, 0, 0);
        if (lk == 0) {                // all D rows equal; lanes 0-15 publish
          const int n = 96 * w + 16 * i + l15;
          pre[n >> 8][n & 255] = acc[0];
        }
      }
      lds_barrier();

      if (t < 256) {
        float aR = pre[0][t], aZ = pre[1][t], aNp = pre[2][t];
        float r = sigm(gr + aR + bR);
        float z = sigm(gz + aZ + bZ);
        float nn = tanh_f(gn + r * (aNp + bN));
        float hn = fmaf(z, hprev - nn, nn);    // (1-z)*n + z*h
        hprev = hn;
        _Float16 hf = (_Float16)hn;
        hbuf[cur ^ 1][t] = hf;
        wob[(size_t)ts * D + t] = hf;          // f16 history (coalesced)
        const int tn = ts + 1;
        if (tn & (CHUNK - 1)) {                // within chunk: prefetch
          const float* gxn = gxb + (size_t)tn * G;
          gr = gxn[t]; gz = gxn[D + t]; gn = gxn[2 * D + t];
        }
      }
      lds_barrier();
    }
  }

  // ===== fused epilogue: attn-pool (f16 history) + sentence GRU =====
  asm volatile("s_waitcnt vmcnt(0)" ::: "memory");   // wo16 stores done
  __syncthreads();

  // logits: wave w handles rows [64w, 64w+64); f16 rows, 512B each
  {
    const float ua0 = uaw[lane], ua1 = uaw[lane + 64];
    const float ua2 = uaw[lane + 128], ua3 = uaw[lane + 192];
    for (int r = 0; r < 64; ++r) {
      const int tt = 64 * w + r;
      const _Float16* row = wob + (size_t)tt * D;
      float p = (float)row[lane] * ua0 + (float)row[lane + 64] * ua1 +
                (float)row[lane + 128] * ua2 + (float)row[lane + 192] * ua3;
#pragma unroll
      for (int off = 32; off; off >>= 1) p += __shfl_down(p, off);
      if (lane == 0) lg[tt] = p;               // ua_b cancels in softmax
    }
  }
  __syncthreads();

  // softmax over 512 logits (thread t owns lg[t])
  {
    float v = lg[t];
    float m = v;
#pragma unroll
    for (int off = 32; off; off >>= 1) m = fmaxf(m, __shfl_xor(m, off));
    if (lane == 0) red[w] = m;
    __syncthreads();
    m = red[0];
#pragma unroll
    for (int i = 1; i < 8; ++i) m = fmaxf(m, red[i]);
    float e = __expf(v - m);
    float s = e;
#pragma unroll
    for (int off = 32; off; off >>= 1) s += __shfl_xor(s, off);
    if (lane == 0) red[8 + w] = s;
    __syncthreads();
    s = red[8];
#pragma unroll
    for (int i = 9; i < 16; ++i) s += red[i];
    lg[t] = e * (1.0f / s);
  }
  __syncthreads();

  // weighted sum over f16 history: half 0 sums ts in [0,256), half 1 rest
  {
    const int d = t & 255, half = t >> 8;
    float acc = 0.0f;
    const _Float16* bbp = wob + (size_t)half * 256 * D;
    const float* lgh = lg + half * 256;
#pragma unroll 4
    for (int k = 0; k < 256; ++k)
      acc = fmaf(lgh[k], (float)bbp[(size_t)k * D + d], acc);
    if (half == 1) part[d] = acc;
    __syncthreads();
    if (half == 0) ut[d] = acc + part[d];
    __syncthreads();
  }

  // sentence GRU (T=1, h0=0) -> out = (1-z)*n
  if (t < 256) {
    const int d = t;
    const float* wr = sWih + (size_t)d * D;
    const float* wz = sWih + (size_t)(D + d) * D;
    const float* wn = sWih + (size_t)(2 * D + d) * D;
    float ar = 0.0f, az = 0.0f, an = 0.0f;
    for (int k = 0; k < D; k += 4) {
      float4 vr = *(const float4*)(wr + k);
      float4 vz = *(const float4*)(wz + k);
      float4 vn = *(const float4*)(wn + k);
      float u0 = ut[k], u1 = ut[k + 1], u2 = ut[k + 2], u3 = ut[k + 3];
      ar += vr.x * u0 + vr.y * u1 + vr.z * u2 + vr.w * u3;
      az += vz.x * u0 + vz.y * u1 + vz.z * u2 + vz.w * u3;
      an += vn.x * u0 + vn.y * u1 + vn.z * u2 + vn.w * u3;
    }
    float r = sigm(ar + sbih[d] + sbhh[d]);
    float z = sigm(az + sbih[D + d] + sbhh[D + d]);
    float n = tanh_f(an + sbih[2 * D + d] + r * sbhh[2 * D + d]);
    out[(size_t)b * D + d] = (1.0f - z) * n;
  }
}

// ---------------------------------------------------------------------------
extern "C" void kernel_launch(void* const* d_in, const int* in_sizes, int n_in,
                              void* d_out, int out_size, void* d_ws, size_t ws_size,
                              hipStream_t stream) {
  const int* tokens    = (const int*)d_in[0];
  const float* embed   = (const float*)d_in[1];
  const float* wg_Wih  = (const float*)d_in[2];
  const float* wg_Whh  = (const float*)d_in[3];
  const float* wg_bih  = (const float*)d_in[4];
  const float* wg_bhh  = (const float*)d_in[5];
  const float* ua_w    = (const float*)d_in[6];
  // d_in[7] ua_b: softmax shift-invariant -> unused
  const float* sg_Wih  = (const float*)d_in[8];
  // d_in[9] sg_Whh: h0 == 0 -> unused
  const float* sg_bih  = (const float*)d_in[10];
  const float* sg_bhh  = (const float*)d_in[11];
  // d_in[12..13] da_w/da_b: softmax over T=1 -> unused
  float* out = (float*)d_out;

  char* ws = (char*)d_ws;
  const size_t GXB = (size_t)NUTT * L * G * 4;                 // 96 MB
  float* gx = (float*)ws;
  _Float16* whi = (_Float16*)(ws + GXB);                       // 384 KB
  _Float16* wlo = whi + (size_t)G * D;                         // 384 KB
  int* cnt = (int*)(ws + GXB + (size_t)2 * G * D * 2);         // 16 KB flags
  _Float16* wo16 = (_Float16*)(ws + GXB + (size_t)2 * G * D * 2 + 16384);

  pack_wih<<<G, 256, 0, stream>>>(wg_Wih, whi, wlo, cnt);
  hran_mega<<<NUTT + NGEMM, 512, 0, stream>>>(
      tokens, embed, whi, wlo, wg_bih, wg_Whh, wg_bhh, ua_w,
      sg_Wih, sg_bih, sg_bhh, gx, wo16, cnt, out);
}

// Round 12
// 772.121 us; speedup vs baseline: 1.0927x; 1.0053x over previous
//
#include <hip/hip_runtime.h>

typedef _Float16 f16x8 __attribute__((ext_vector_type(8)));
typedef float f32x4 __attribute__((ext_vector_type(4)));

constexpr int D = 256;
constexpr int NUTT = 64;
constexpr int L = 512;
constexpr int G = 768;           // 3*D
constexpr int CHUNK = 128;       // timesteps per producer chunk
constexpr int NCH = L / CHUNK;   // 4 chunks per utterance
constexpr int NBLK = 6;          // 128-col n-blocks over G=768
constexpr int NGEMM = NCH * NUTT * NBLK;   // 1536 producer blocks

// LDS-only barrier: orders ds_* ops across the workgroup WITHOUT draining
// vmcnt — global prefetch loads / wo16 stores stay in flight across steps.
__device__ __forceinline__ void lds_barrier() {
  asm volatile("s_waitcnt lgkmcnt(0)\n\ts_barrier" ::: "memory");
}

__device__ __forceinline__ float fast_rcp(float x) {
  return __builtin_amdgcn_rcpf(x);
}
__device__ __forceinline__ float sigm(float x) {
  return fast_rcp(1.0f + __expf(-x));
}
__device__ __forceinline__ float tanh_f(float x) {
  float ax = fabsf(x);
  float e = __expf(-2.0f * ax);
  float r = (1.0f - e) * fast_rcp(1.0f + e);
  return copysignf(r, x);
}

// ---------------------------------------------------------------------------
// Kernel A: pack Wih (f32) -> f16 hi/lo in MFMA fragment order (R9-verified,
// inverted map: thread = dst index, coalesced stores).
// Block 0 also zeroes the producer-consumer chunk flags (64B-padded).
// ---------------------------------------------------------------------------
__global__ __launch_bounds__(256) void pack_wih(
    const float* __restrict__ Wih, _Float16* __restrict__ hi,
    _Float16* __restrict__ lo, int* cnt) {
  if (blockIdx.x == 0) cnt[threadIdx.x << 4] = 0;
  const int d = blockIdx.x * 256 + threadIdx.x;    // grid = 768 blocks
  const int j = d & 7;
  const int l15 = (d >> 3) & 15;
  const int lk = (d >> 7) & 3;
  const int f = (d >> 9) & 7;
  const int it = d >> 12;
  const int g = 16 * it + l15;
  const int k = 32 * f + 8 * lk + j;
  float v = Wih[g * 256 + k];
  _Float16 h = (_Float16)v;
  hi[d] = h;
  lo[d] = (_Float16)(v - (float)h);
}

// ---------------------------------------------------------------------------
// Mega-kernel — R11 structure byte-identical except one change:
// CONSUMER WAVES RUN AT s_setprio(1) (T5). R11 counters localized ~75 µs
// of scan slowdown to producer blocks co-resident on consumer CUs (both
// roles fit 2/CU; producers steal issue slots during the overlap window).
// Per-role LDS padding is impossible (one kernel = one static LDS size),
// so wave priority is the remaining lever: consumers at prio 1, producers
// at default 0 -> on shared CUs the latency-critical scan wins issue
// arbitration; only raw L2/HBM bandwidth contention remains.
// ---------------------------------------------------------------------------
__global__ __launch_bounds__(512, 2) void hran_mega(
    const int* __restrict__ tokens, const float* __restrict__ embed,
    const _Float16* __restrict__ whi, const _Float16* __restrict__ wlo,
    const float* __restrict__ bih,   // wg_bih
    const float* __restrict__ Whh,   // wg_Whh
    const float* __restrict__ bhh,   // wg_bhh
    const float* __restrict__ uaw,   // ua_w
    const float* __restrict__ sWih, const float* __restrict__ sbih,
    const float* __restrict__ sbhh,
    float* __restrict__ gx,          // [NUTT][L][G]
    _Float16* __restrict__ wo16,     // [NUTT][L][D] f16 h history
    int* cnt,                        // 256 flags, 64B-padded
    float* __restrict__ out) {       // [NUTT][D]
  __shared__ __align__(16) _Float16 hbuf[2][D];   // f16 h, double-buffered
  __shared__ float pre[3][D];                     // [comp][d] = aR/aZ/aN
  __shared__ float lg[L];
  __shared__ float red[16];
  __shared__ float part[D];
  __shared__ __align__(16) float ut[D];

  const int bx = blockIdx.x;
  const int t = threadIdx.x;
  const int w = t >> 6;               // wave 0..7
  const int lane = t & 63;
  const int l15 = lane & 15;
  const int lk = lane >> 4;

  if (bx >= NUTT) {
    // =================== gemm producer role (R7/R8-verified) =============
    const int gbx = bx - NUTT;
    const int c = gbx / (NUTT * NBLK);         // chunk-major
    const int rem = gbx % (NUTT * NBLK);
    const int u = rem / NBLK;
    const int nb = rem % NBLK;
    const int m0 = u * L + c * CHUNK;          // 128 rows (8 waves x 16)
    const int n0 = nb * 128;
    const int it0 = nb * 8;

    const int tok = tokens[m0 + 16 * w + l15];
    const float* arow = embed + (size_t)tok * D;
    const f16x8* Bh = (const f16x8*)whi;
    const f16x8* Bl = (const f16x8*)wlo;
    const int fragbase = lk * 16 + l15;

    f32x4 acc[8] = {};
#pragma unroll
    for (int f = 0; f < 8; ++f) {
      const float* ap = arow + 32 * f + 8 * lk;
      float4 v0 = *(const float4*)(ap);
      float4 v1 = *(const float4*)(ap + 4);
      float av[8] = {v0.x, v0.y, v0.z, v0.w, v1.x, v1.y, v1.z, v1.w};
      f16x8 ahi, alo;
#pragma unroll
      for (int j = 0; j < 8; ++j) {
        _Float16 h = (_Float16)av[j];
        ahi[j] = h;
        alo[j] = (_Float16)(av[j] - (float)h);
      }
#pragma unroll
      for (int i = 0; i < 8; ++i) {
        const int frag = ((it0 + i) * 8 + f) * 64 + fragbase;
        f16x8 bhi = Bh[frag];
        f16x8 blo = Bl[frag];
        acc[i] = __builtin_amdgcn_mfma_f32_16x16x32_f16(ahi, bhi, acc[i], 0, 0, 0);
        acc[i] = __builtin_amdgcn_mfma_f32_16x16x32_f16(alo, bhi, acc[i], 0, 0, 0);
        acc[i] = __builtin_amdgcn_mfma_f32_16x16x32_f16(ahi, blo, acc[i], 0, 0, 0);
      }
    }
#pragma unroll
    for (int i = 0; i < 8; ++i) {
      const int n = n0 + 16 * i + l15;
      const float bb = bih[n];
#pragma unroll
      for (int reg = 0; reg < 4; ++reg) {
        const int m = m0 + 16 * w + 4 * lk + reg;
        gx[(size_t)m * G + n] = acc[i][reg] + bb;
      }
    }
    __syncthreads();                 // drains vmcnt: all stores issued
    if (t == 0)
      __hip_atomic_fetch_add(&cnt[((u << 2) + c) << 4], 1,
                             __ATOMIC_RELEASE, __HIP_MEMORY_SCOPE_AGENT);
    return;
  }

  // ====================== gru consumer role ==============================
  const int b = bx;
  __builtin_amdgcn_s_setprio(1);      // T5: outprioritize co-resident
                                      // producer waves for issue slots

  // ---- Bf[i][f][j] = Whh[96w + 16i + l15][32f + 8lk + j], f16 ----
  f16x8 Bf[6][8];
#pragma unroll
  for (int i = 0; i < 6; ++i) {
    const float* row = Whh + (size_t)(96 * w + 16 * i + l15) * D + 8 * lk;
#pragma unroll
    for (int f = 0; f < 8; ++f) {
      float4 v0 = *(const float4*)(row + 32 * f);
      float4 v1 = *(const float4*)(row + 32 * f + 4);
      Bf[i][f] = f16x8{(_Float16)v0.x, (_Float16)v0.y,
                       (_Float16)v0.z, (_Float16)v0.w,
                       (_Float16)v1.x, (_Float16)v1.y,
                       (_Float16)v1.z, (_Float16)v1.w};
    }
  }

  float bR = 0.0f, bZ = 0.0f, bN = 0.0f;
  float gr = 0.0f, gz = 0.0f, gn = 0.0f;
  float hprev = 0.0f;
  float* gxb = gx + (size_t)b * L * G;
  _Float16* wob = wo16 + (size_t)b * L * D;
  if (t < 256) {
    bR = bhh[t]; bZ = bhh[D + t]; bN = bhh[2 * D + t];
    hbuf[0][t] = (_Float16)0.0f;
  }
  __syncthreads();

  for (int c = 0; c < NCH; ++c) {
    // wait for this utterance's chunk c (6 producer blocks)
    if (t == 0) {
      while (__hip_atomic_load(&cnt[((b << 2) + c) << 4],
                               __ATOMIC_ACQUIRE,
                               __HIP_MEMORY_SCOPE_AGENT) < NBLK)
        __builtin_amdgcn_s_sleep(8);
    }
    __syncthreads();
    __threadfence();
    if (t < 256) {                   // chunk-entry g* load
      const float* gc = gxb + (size_t)(CHUNK * c) * G;
      gr = gc[t]; gz = gc[D + t]; gn = gc[2 * D + t];
    }

    for (int tsl = 0; tsl < CHUNK; ++tsl) {
      const int ts = CHUNK * c + tsl;
      const int cur = ts & 1;
      const _Float16* hb = hbuf[cur];
      f16x8 A[8];
#pragma unroll
      for (int f = 0; f < 8; ++f)
        A[f] = *(const f16x8*)(hb + 32 * f + 8 * lk);

#pragma unroll
      for (int i = 0; i < 6; ++i) {
        f32x4 acc = {0.0f, 0.0f, 0.0f, 0.0f};
#pragma unroll
        for (int f = 0; f < 8; ++f)
          acc = __builtin_amdgcn_mfma_f32_16x16x32_f16(A[f], Bf[i][f], acc,
                                                       0, 0, 0);
        if (lk == 0) {                // all D rows equal; lanes 0-15 publish
          const int n = 96 * w + 16 * i + l15;
          pre[n >> 8][n & 255] = acc[0];
        }
      }
      lds_barrier();

      if (t < 256) {
        float aR = pre[0][t], aZ = pre[1][t], aNp = pre[2][t];
        float r = sigm(gr + aR + bR);
        float z = sigm(gz + aZ + bZ);
        float nn = tanh_f(gn + r * (aNp + bN));
        float hn = fmaf(z, hprev - nn, nn);    // (1-z)*n + z*h
        hprev = hn;
        _Float16 hf = (_Float16)hn;
        hbuf[cur ^ 1][t] = hf;
        wob[(size_t)ts * D + t] = hf;          // f16 history (coalesced)
        const int tn = ts + 1;
        if (tn & (CHUNK - 1)) {                // within chunk: prefetch
          const float* gxn = gxb + (size_t)tn * G;
          gr = gxn[t]; gz = gxn[D + t]; gn = gxn[2 * D + t];
        }
      }
      lds_barrier();
    }
  }

  // ===== fused epilogue: attn-pool (f16 history) + sentence GRU =====
  asm volatile("s_waitcnt vmcnt(0)" ::: "memory");   // wo16 stores done
  __syncthreads();

  // logits: wave w handles rows [64w, 64w+64); f16 rows, 512B each
  {
    const float ua0 = uaw[lane], ua1 = uaw[lane + 64];
    const float ua2 = uaw[lane + 128], ua3 = uaw[lane + 192];
    for (int r = 0; r < 64; ++r) {
      const int tt = 64 * w + r;
      const _Float16* row = wob + (size_t)tt * D;
      float p = (float)row[lane] * ua0 + (float)row[lane + 64] * ua1 +
                (float)row[lane + 128] * ua2 + (float)row[lane + 192] * ua3;
#pragma unroll
      for (int off = 32; off; off >>= 1) p += __shfl_down(p, off);
      if (lane == 0) lg[tt] = p;               // ua_b cancels in softmax
    }
  }
  __syncthreads();

  // softmax over 512 logits (thread t owns lg[t])
  {
    float v = lg[t];
    float m = v;
#pragma unroll
    for (int off = 32; off; off >>= 1) m = fmaxf(m, __shfl_xor(m, off));
    if (lane == 0) red[w] = m;
    __syncthreads();
    m = red[0];
#pragma unroll
    for (int i = 1; i < 8; ++i) m = fmaxf(m, red[i]);
    float e = __expf(v - m);
    float s = e;
#pragma unroll
    for (int off = 32; off; off >>= 1) s += __shfl_xor(s, off);
    if (lane == 0) red[8 + w] = s;
    __syncthreads();
    s = red[8];
#pragma unroll
    for (int i = 9; i < 16; ++i) s += red[i];
    lg[t] = e * (1.0f / s);
  }
  __syncthreads();

  // weighted sum over f16 history: half 0 sums ts in [0,256), half 1 rest
  {
    const int d = t & 255, half = t >> 8;
    float acc = 0.0f;
    const _Float16* bbp = wob + (size_t)half * 256 * D;
    const float* lgh = lg + half * 256;
#pragma unroll 4
    for (int k = 0; k < 256; ++k)
      acc = fmaf(lgh[k], (float)bbp[(size_t)k * D + d], acc);
    if (half == 1) part[d] = acc;
    __syncthreads();
    if (half == 0) ut[d] = acc + part[d];
    __syncthreads();
  }

  // sentence GRU (T=1, h0=0) -> out = (1-z)*n
  if (t < 256) {
    const int d = t;
    const float* wr = sWih + (size_t)d * D;
    const float* wz = sWih + (size_t)(D + d) * D;
    const float* wn = sWih + (size_t)(2 * D + d) * D;
    float ar = 0.0f, az = 0.0f, an = 0.0f;
    for (int k = 0; k < D; k += 4) {
      float4 vr = *(const float4*)(wr + k);
      float4 vz = *(const float4*)(wz + k);
      float4 vn = *(const float4*)(wn + k);
      float u0 = ut[k], u1 = ut[k + 1], u2 = ut[k + 2], u3 = ut[k + 3];
      ar += vr.x * u0 + vr.y * u1 + vr.z * u2 + vr.w * u3;
      az += vz.x * u0 + vz.y * u1 + vz.z * u2 + vz.w * u3;
      an += vn.x * u0 + vn.y * u1 + vn.z * u2 + vn.w * u3;
    }
    float r = sigm(ar + sbih[d] + sbhh[d]);
    float z = sigm(az + sbih[D + d] + sbhh[D + d]);
    float n = tanh_f(an + sbih[2 * D + d] + r * sbhh[2 * D + d]);
    out[(size_t)b * D + d] = (1.0f - z) * n;
  }
}

// ---------------------------------------------------------------------------
extern "C" void kernel_launch(void* const* d_in, const int* in_sizes, int n_in,
                              void* d_out, int out_size, void* d_ws, size_t ws_size,
                              hipStream_t stream) {
  const int* tokens    = (const int*)d_in[0];
  const float* embed   = (const float*)d_in[1];
  const float* wg_Wih  = (const float*)d_in[2];
  const float* wg_Whh  = (const float*)d_in[3];
  const float* wg_bih  = (const float*)d_in[4];
  const float* wg_bhh  = (const float*)d_in[5];
  const float* ua_w    = (const float*)d_in[6];
  // d_in[7] ua_b: softmax shift-invariant -> unused
  const float* sg_Wih  = (const float*)d_in[8];
  // d_in[9] sg_Whh: h0 == 0 -> unused
  const float* sg_bih  = (const float*)d_in[10];
  const float* sg_bhh  = (const float*)d_in[11];
  // d_in[12..13] da_w/da_b: softmax over T=1 -> unused
  float* out = (float*)d_out;

  char* ws = (char*)d_ws;
  const size_t GXB = (size_t)NUTT * L * G * 4;                 // 96 MB
  float* gx = (float*)ws;
  _Float16* whi = (_Float16*)(ws + GXB);                       // 384 KB
  _Float16* wlo = whi + (size_t)G * D;                         // 384 KB
  int* cnt = (int*)(ws + GXB + (size_t)2 * G * D * 2);         // 16 KB flags
  _Float16* wo16 = (_Float16*)(ws + GXB + (size_t)2 * G * D * 2 + 16384);

  pack_wih<<<G, 256, 0, stream>>>(wg_Wih, whi, wlo, cnt);
  hran_mega<<<NUTT + NGEMM, 512, 0, stream>>>(
      tokens, embed, whi, wlo, wg_bih, wg_Whh, wg_bhh, ua_w,
      sg_Wih, sg_bih, sg_bhh, gx, wo16, cnt, out);
}